// Round 14
// baseline (1431.078 us; speedup 1.0000x reference)
//
#include <hip/hip_runtime.h>
#include <hip/hip_bf16.h>
#include <stdint.h>

// R14: fused reduce, re-planned to fit proven ws (~358MB). Order: megadual ->
// [De=wreg] expert downs in TWO 4-expert halves (Wed half converts into dead
// xb, 23.1<=33.6MB) -> Wsd into dead He -> downfuse (shared down + Sigma De,
// same add order as reduce4; fp32 mem round-trip exact => bitwise-identical).
// Downs reverted to proven 128^2 cores (R13's down8 was neutral/worse).

typedef float f32x4 __attribute__((ext_vector_type(4)));
typedef int   i32x4 __attribute__((ext_vector_type(4)));
typedef __hip_bfloat16 bf16;

#define DEV __device__ __forceinline__

DEV void mfma16(f32x4& c, const i32x4& a, const i32x4& b) {
    asm("v_mfma_f32_16x16x32_bf16 %0, %1, %2, %0" : "+v"(c) : "v"(a), "v"(b));
}

template<int ROWS>
DEV void stage(const bf16* gtile, long ldK, char* lds, int tid) {
    const int wid = tid >> 6, lane = tid & 63;
    const int swz = ((lane & 7) ^ (lane >> 3)) << 4;
    constexpr int NISS = (ROWS * 128) / 4096;
    #pragma unroll
    for (int i = 0; i < NISS; i++) {
        const int o = i * 4096 + wid * 1024;
        const int row = (o >> 7) + (lane >> 3);
        const char* ga = (const char*)gtile + (long)row * (ldK * 2) + swz;
        __builtin_amdgcn_global_load_lds(
            (const __attribute__((address_space(1))) void*)ga,
            (__attribute__((address_space(3))) void*)(lds + o), 16, 0, 0);
    }
}

template<int ROWS>
DEV void stage_idx(const char* base, const long* roff, int ktb, char* lds,
                   int tid, int swz) {
    const int wid = tid >> 6;
    constexpr int NISS = (ROWS * 128) / 4096;
    #pragma unroll
    for (int i = 0; i < NISS; i++) {
        const int o = i * 4096 + wid * 1024;
        const char* ga = base + roff[i] + ktb + swz;
        __builtin_amdgcn_global_load_lds(
            (const __attribute__((address_space(1))) void*)ga,
            (__attribute__((address_space(3))) void*)(lds + o), 16, 0, 0);
    }
}

DEV i32x4 ldsfrag(const char* lds, int row, int kbyte) {
    const int off = (row << 7) + (kbyte ^ ((row & 7) << 4));
    return *(const i32x4*)(lds + off);
}

// ========== vectorized transpose-convert core (64x64 tile) ==========
DEV void tcore(unsigned short (*t)[72], const float* __restrict__ src,
               bf16* __restrict__ dst, long Cd, long dld, int cb, int rb,
               int tid) {
    const int s = tid & 15, g = tid >> 4;
    #pragma unroll
    for (int i = 0; i < 4; i++) {
        const int r = i * 16 + g;
        const float4 v = *(const float4*)(src + (long)(rb + r) * Cd + cb + 4 * s);
        union { bf16 h[4]; ushort4 u; } cu;
        cu.h[0] = __float2bfloat16(v.x); cu.h[1] = __float2bfloat16(v.y);
        cu.h[2] = __float2bfloat16(v.z); cu.h[3] = __float2bfloat16(v.w);
        *(ushort4*)&t[r][4 * s] = cu.u;
    }
    __syncthreads();
    #pragma unroll
    for (int i = 0; i < 4; i++) {
        const int c = i * 16 + g;
        ushort4 u;
        u.x = t[4 * s + 0][c]; u.y = t[4 * s + 1][c];
        u.z = t[4 * s + 2][c]; u.w = t[4 * s + 3][c];
        *(ushort4*)((unsigned short*)dst + (long)(cb + c) * dld + rb + 4 * s) = u;
    }
}

__global__ __launch_bounds__(256) void convt_gu(const float* __restrict__ egw,
        const float* __restrict__ euw, const float* __restrict__ sgw,
        const float* __restrict__ suw, bf16* __restrict__ Wea,
        bf16* __restrict__ Web, bf16* __restrict__ Wsa, bf16* __restrict__ Wsb) {
    __shared__ unsigned short t[64][72];
    const int z = blockIdx.z, cb = blockIdx.x * 64, rb = blockIdx.y * 64;
    const float* src; bf16* dst; long Cd;
    if (z < 8)       { src = egw + (long)z * 2048 * 1408;        dst = Wea + (long)z * 1408 * 2048;        Cd = 1408; }
    else if (z < 16) { src = euw + (long)(z - 8) * 2048 * 1408;  dst = Web + (long)(z - 8) * 1408 * 2048;  Cd = 1408; }
    else if (z < 20) { src = sgw + (long)(z - 16) * 1408;        dst = Wsa + (long)(z - 16) * 1408 * 2048; Cd = 5632; }
    else             { src = suw + (long)(z - 20) * 1408;        dst = Wsb + (long)(z - 20) * 1408 * 2048; Cd = 5632; }
    tcore(t, src, dst, Cd, 2048, cb, rb, threadIdx.x);
}

__global__ __launch_bounds__(256) void convt_dns(const float* __restrict__ sdw,
        bf16* __restrict__ Wsd) {
    __shared__ unsigned short t[64][72];
    const int z = blockIdx.z, cb = blockIdx.x * 64, rb = blockIdx.y * 64;
    tcore(t, sdw + (long)z * 1408 * 2048, Wsd + (long)z * 1408,
          2048, 5632, cb, rb, threadIdx.x);
}
// converts 4 experts starting at edw0 into Wed[0..4) slots
__global__ __launch_bounds__(256) void convt_dne(const float* __restrict__ edw0,
        bf16* __restrict__ Wed) {
    __shared__ unsigned short t[64][72];
    const int z = blockIdx.z, cb = blockIdx.x * 64, rb = blockIdx.y * 64;
    tcore(t, edw0 + (long)z * 1408 * 2048, Wed + (long)z * 2048 * 1408,
          2048, 1408, cb, rb, threadIdx.x);
}

// ---------------- generic tcvt (deep fallback only) ----------------
__global__ __launch_bounds__(256) void tcvt(const float* __restrict__ srcA,
        bf16* __restrict__ dstA, const float* __restrict__ srcB,
        bf16* __restrict__ dstB, int Cd, long dld, long sz, long dz,
        int zsplit) {
    __shared__ float t[64][65];
    long z = blockIdx.z;
    const float* src; bf16* dst;
    if ((int)z < zsplit) { src = srcA; dst = dstA; }
    else { src = srcB; dst = dstB; z -= zsplit; }
    src += z * sz; dst += z * dz;
    const int cb = blockIdx.x * 64, rb = blockIdx.y * 64;
    const int tx = threadIdx.x & 63, ty = threadIdx.x >> 6;
    #pragma unroll
    for (int i = 0; i < 16; i++) {
        const int r = ty + i * 4;
        t[r][tx] = src[(long)(rb + r) * Cd + cb + tx];
    }
    __syncthreads();
    #pragma unroll
    for (int i = 0; i < 16; i++) {
        const int c = ty + i * 4;
        dst[(long)(cb + c) * dld + rb + tx] = __float2bfloat16(t[tx][c]);
    }
}

// ------- fused x convert + router -----
__global__ __launch_bounds__(256) void cvtrt(const float* __restrict__ x,
        const float* __restrict__ gw, const float* __restrict__ segw,
        bf16* __restrict__ xb, int* __restrict__ tidx, float* __restrict__ tw,
        float* __restrict__ sg) {
    const int lane = threadIdx.x & 63;
    const long t = (long)blockIdx.x * 4 + (threadIdx.x >> 6);
    const float4* xr = (const float4*)(x + t * 2048);
    ushort4* xo = (ushort4*)(xb + t * 2048);
    float a[9];
    #pragma unroll
    for (int e = 0; e < 9; e++) a[e] = 0.f;
    #pragma unroll
    for (int i = 0; i < 8; i++) {
        const int c4 = i * 64 + lane;
        const float4 v = xr[c4];
        union { bf16 h[4]; ushort4 u; } cu;
        cu.h[0] = __float2bfloat16(v.x); cu.h[1] = __float2bfloat16(v.y);
        cu.h[2] = __float2bfloat16(v.z); cu.h[3] = __float2bfloat16(v.w);
        xo[c4] = cu.u;
        const int c = c4 * 4;
        const float xv[4] = { v.x, v.y, v.z, v.w };
        #pragma unroll
        for (int j = 0; j < 4; j++) {
            const float4* g4 = (const float4*)(gw + (long)(c + j) * 8);
            const float4 g0 = g4[0], g1 = g4[1];
            a[0] += xv[j] * g0.x; a[1] += xv[j] * g0.y;
            a[2] += xv[j] * g0.z; a[3] += xv[j] * g0.w;
            a[4] += xv[j] * g1.x; a[5] += xv[j] * g1.y;
            a[6] += xv[j] * g1.z; a[7] += xv[j] * g1.w;
            a[8] += xv[j] * segw[c + j];
        }
    }
    #pragma unroll
    for (int e = 0; e < 9; e++) {
        #pragma unroll
        for (int o = 32; o; o >>= 1) a[e] += __shfl_xor(a[e], o, 64);
    }
    if (lane == 0) {
        float m = a[0];
        #pragma unroll
        for (int e = 1; e < 8; e++) m = fmaxf(m, a[e]);
        float p[8]; float s = 0.f;
        #pragma unroll
        for (int e = 0; e < 8; e++) { p[e] = expf(a[e] - m); s += p[e]; }
        #pragma unroll
        for (int e = 0; e < 8; e++) p[e] /= s;
        bool used[8] = {false,false,false,false,false,false,false,false};
        float wsum = 0.f; int idx[4]; float wv[4];
        for (int k = 0; k < 4; k++) {       // strict > : lowest index on ties
            float best = -1.f; int bi = 0;
            for (int e = 0; e < 8; e++)
                if (!used[e] && p[e] > best) { best = p[e]; bi = e; }
            used[bi] = true; idx[k] = bi; wv[k] = best; wsum += best;
        }
        int4 iv; float4 wv4;
        iv.x = idx[0]; iv.y = idx[1]; iv.z = idx[2]; iv.w = idx[3];
        wv4.x = wv[0] / wsum; wv4.y = wv[1] / wsum;
        wv4.z = wv[2] / wsum; wv4.w = wv[3] / wsum;
        ((int4*)tidx)[t] = iv;
        ((float4*)tw)[t] = wv4;
        sg[t] = 1.f / (1.f + expf(-a[8]));
    }
}

// ------ per-expert ordered token lists + inverse slot map -------------------
__global__ __launch_bounds__(256) void build_lists(const int* __restrict__ tidx,
        const float* __restrict__ tw, int* __restrict__ tok,
        float* __restrict__ wl, int* __restrict__ cnt, int* __restrict__ inv,
        int N) {
    const int e = blockIdx.x;
    const int tid = threadIdx.x;
    const int per = N / 256;
    __shared__ int csum[256];
    int c = 0;
    for (int i = 0; i < per; i++) {
        const int4 id4 = ((const int4*)tidx)[tid * per + i];
        if (id4.x == e || id4.y == e || id4.z == e || id4.w == e) c++;
    }
    csum[tid] = c;
    __syncthreads();
    for (int o = 1; o < 256; o <<= 1) {
        const int v = (tid >= o) ? csum[tid - o] : 0;
        __syncthreads();
        csum[tid] += v;
        __syncthreads();
    }
    int pos = csum[tid] - c;
    if (tid == 255) cnt[e] = csum[255];
    for (int i = 0; i < per; i++) {
        const int t = tid * per + i;
        const int4   id4 = ((const int4*)tidx)[t];
        const float4 w4  = ((const float4*)tw)[t];
        float w = 0.f; int hit = 0; int k = 0;
        if      (id4.x == e) { w = w4.x; hit = 1; k = 0; }
        else if (id4.y == e) { w = w4.y; hit = 1; k = 1; }
        else if (id4.z == e) { w = w4.z; hit = 1; k = 2; }
        else if (id4.w == e) { w = w4.w; hit = 1; k = 3; }
        if (hit) {
            tok[(long)e * N + pos] = t;
            wl[(long)e * N + pos] = w;
            inv[t * 4 + k] = pos;
            pos++;
        }
    }
}

__global__ void scan8(const int* __restrict__ cnt, int* __restrict__ starts) {
    if (threadIdx.x == 0) {
        int s = 0;
        for (int e = 0; e < 8; e++) { starts[e] = s; s += cnt[e]; }
        starts[8] = s;
    }
}

// ======== mega dual gate/up GEMM (unchanged, verified) ==========
__global__ __launch_bounds__(256) void megadual(const bf16* __restrict__ A0,
        const int* __restrict__ tok, const int* __restrict__ cnt,
        const int* __restrict__ starts, int nExpZ, int e0,
        const bf16* __restrict__ Wea, const bf16* __restrict__ Web, long ebz,
        const bf16* __restrict__ Wsa, const bf16* __restrict__ Wsb,
        bf16* __restrict__ He, bf16* __restrict__ Hs,
        const float* __restrict__ wl, const float* __restrict__ sg, int K) {
    __shared__ __align__(128) char Al[16384];
    __shared__ __align__(128) char Gl[8192];
    __shared__ __align__(128) char Ul[8192];
    const int z = blockIdx.z;
    const bf16 *BG, *BU; bf16* H; long hld, n0; const float* sc;
    const int* ridx; int Me;
    if (z < nExpZ) {
        const int e = e0 + z;
        Me = cnt[e];
        ridx = tok + (long)e * 8192;
        BG = Wea + (long)z * ebz; BU = Web + (long)z * ebz;
        H = He + ((long)starts[e] - starts[e0]) * 1408;
        hld = 1408; sc = wl + (long)e * 8192;
        n0 = (long)blockIdx.y * 64;
    } else {
        Me = 8192; ridx = nullptr;
        BG = Wsa; BU = Wsb; H = Hs; hld = 5632; sc = sg;
        n0 = (long)((z - nExpZ) * gridDim.y + blockIdx.y) * 64;
    }
    const long m0 = (long)blockIdx.x * 128;
    if (m0 >= Me) return;
    const int tid = threadIdx.x, lane = tid & 63, wid = tid >> 6;
    const int wm = (wid >> 1) * 64, wn = (wid & 1) * 32;
    const int l15 = lane & 15, lhi = lane >> 4;
    const int swz = ((lane & 7) ^ (lane >> 3)) << 4;
    long roffA[4];
    #pragma unroll
    for (int i = 0; i < 4; i++) {
        const int rit = ((i * 4096 + wid * 1024) >> 7) + (lane >> 3);
        int g = (int)m0 + rit;
        if (ridx) g = ridx[g < Me ? g : Me - 1];
        roffA[i] = (long)g * (K * 2);
    }
    f32x4 ag[4][2] = {}; f32x4 au[4][2] = {};
    for (int kt = 0; kt < K; kt += 64) {
        stage_idx<128>((const char*)A0, roffA, kt * 2, Al, tid, swz);
        stage<64>(BG + n0 * K + kt, (long)K, Gl, tid);
        stage<64>(BU + n0 * K + kt, (long)K, Ul, tid);
        __syncthreads();
        #pragma unroll
        for (int ks = 0; ks < 2; ks++) {
            const int kb = ks * 64 + lhi * 16;
            i32x4 af[4], bg[2], bu[2];
            #pragma unroll
            for (int mi = 0; mi < 4; mi++) af[mi] = ldsfrag(Al, wm + mi * 16 + l15, kb);
            #pragma unroll
            for (int ni = 0; ni < 2; ni++) {
                bg[ni] = ldsfrag(Gl, wn + ni * 16 + l15, kb);
                bu[ni] = ldsfrag(Ul, wn + ni * 16 + l15, kb);
            }
            #pragma unroll
            for (int mi = 0; mi < 4; mi++) {
                #pragma unroll
                for (int ni = 0; ni < 2; ni++) {
                    mfma16(ag[mi][ni], af[mi], bg[ni]);
                    mfma16(au[mi][ni], af[mi], bu[ni]);
                }
            }
        }
        __syncthreads();
    }
    asm volatile("s_nop 7\n\ts_nop 7\n\ts_nop 7");
    #pragma unroll
    for (int mi = 0; mi < 4; mi++) {
        #pragma unroll
        for (int r = 0; r < 4; r++) {
            const int pos = (int)m0 + wm + mi * 16 + lhi * 4 + r;
            if (pos < Me) {
                const float s = sc[pos];
                #pragma unroll
                for (int ni = 0; ni < 2; ni++) {
                    const float gv = ag[mi][ni][r], uv = au[mi][ni][r];
                    const float h = (gv / (1.f + expf(-gv))) * uv * s;
                    H[(long)pos * hld + n0 + wn + ni * 16 + l15] = __float2bfloat16(h);
                }
            }
        }
    }
}

// ------ down GEMM (fallback path) ----------
template<int TAG>
__global__ __launch_bounds__(256) void gemm_down_t(const bf16* __restrict__ A,
        const bf16* __restrict__ BT, float* __restrict__ C,
        const int* __restrict__ ridx, const int* __restrict__ cntp, int Mfix,
        const int* __restrict__ starts, int ia, int ib,
        int K, long ldc, int beta) {
    __shared__ __align__(128) char Al[16384];
    __shared__ __align__(128) char Bl[16384];
    const int Me = cntp ? *cntp : Mfix;
    const long m0 = (long)blockIdx.y * 128;
    if (m0 >= Me) return;
    if (starts) A += ((long)starts[ia] - starts[ib]) * K;
    const int tid = threadIdx.x, lane = tid & 63, wid = tid >> 6;
    const long n0 = (long)blockIdx.x * 128;
    const int wm = (wid >> 1) * 64, wn = (wid & 1) * 64;
    const int l15 = lane & 15, lhi = lane >> 4;
    f32x4 acc[4][4] = {};
    for (int kt = 0; kt < K; kt += 64) {
        stage<128>(A  + m0 * K + kt, (long)K, Al, tid);
        stage<128>(BT + n0 * K + kt, (long)K, Bl, tid);
        __syncthreads();
        #pragma unroll
        for (int ks = 0; ks < 2; ks++) {
            const int kb = ks * 64 + lhi * 16;
            i32x4 af[4], bfr[4];
            #pragma unroll
            for (int mi = 0; mi < 4; mi++) af[mi]  = ldsfrag(Al, wm + mi * 16 + l15, kb);
            #pragma unroll
            for (int ni = 0; ni < 4; ni++) bfr[ni] = ldsfrag(Bl, wn + ni * 16 + l15, kb);
            #pragma unroll
            for (int mi = 0; mi < 4; mi++) {
                #pragma unroll
                for (int ni = 0; ni < 4; ni++) mfma16(acc[mi][ni], af[mi], bfr[ni]);
            }
        }
        __syncthreads();
    }
    asm volatile("s_nop 7\n\ts_nop 7\n\ts_nop 7");
    #pragma unroll
    for (int mi = 0; mi < 4; mi++) {
        #pragma unroll
        for (int r = 0; r < 4; r++) {
            const int pos = (int)m0 + wm + mi * 16 + lhi * 4 + r;
            if (pos < Me) {
                const long orow = ridx ? (long)ridx[pos] : (long)pos;
                #pragma unroll
                for (int ni = 0; ni < 4; ni++) {
                    const long ci = orow * ldc + n0 + wn + ni * 16 + l15;
                    float v = acc[mi][ni][r];
                    if (beta) v += C[ci];
                    C[ci] = v;
                }
            }
        }
    }
}

// ====== expert mega-down -> compact bf16 De (proven 128^2 core) ======
// cnt/starts passed pre-offset for half-batches; De indexed by global starts.
__global__ __launch_bounds__(256) void megadown(const bf16* __restrict__ He,
        const bf16* __restrict__ Wd0, long wz, bf16* __restrict__ De,
        const int* __restrict__ cnt, const int* __restrict__ starts, int K) {
    __shared__ __align__(128) char Al[16384];
    __shared__ __align__(128) char Bl[16384];
    const int z = blockIdx.z;
    const int Me = cnt[z];
    const long m0 = (long)blockIdx.y * 128;
    if (m0 >= Me) return;
    const bf16* A  = He + (long)starts[z] * K;
    const bf16* BT = Wd0 + (long)z * wz;
    const int tid = threadIdx.x, lane = tid & 63, wid = tid >> 6;
    const long n0 = (long)blockIdx.x * 128;
    const int wm = (wid >> 1) * 64, wn = (wid & 1) * 64;
    const int l15 = lane & 15, lhi = lane >> 4;
    f32x4 acc[4][4] = {};
    for (int kt = 0; kt < K; kt += 64) {
        stage<128>(A  + m0 * K + kt, (long)K, Al, tid);
        stage<128>(BT + n0 * K + kt, (long)K, Bl, tid);
        __syncthreads();
        #pragma unroll
        for (int ks = 0; ks < 2; ks++) {
            const int kb = ks * 64 + lhi * 16;
            i32x4 af[4], bfr[4];
            #pragma unroll
            for (int mi = 0; mi < 4; mi++) af[mi]  = ldsfrag(Al, wm + mi * 16 + l15, kb);
            #pragma unroll
            for (int ni = 0; ni < 4; ni++) bfr[ni] = ldsfrag(Bl, wn + ni * 16 + l15, kb);
            #pragma unroll
            for (int mi = 0; mi < 4; mi++) {
                #pragma unroll
                for (int ni = 0; ni < 4; ni++) mfma16(acc[mi][ni], af[mi], bfr[ni]);
            }
        }
        __syncthreads();
    }
    asm volatile("s_nop 7\n\ts_nop 7\n\ts_nop 7");
    #pragma unroll
    for (int mi = 0; mi < 4; mi++) {
        #pragma unroll
        for (int r = 0; r < 4; r++) {
            const int pos = (int)m0 + wm + mi * 16 + lhi * 4 + r;
            if (pos < Me) {
                const long orow = (long)starts[z] + pos;
                #pragma unroll
                for (int ni = 0; ni < 4; ni++) {
                    De[orow * 2048 + n0 + wn + ni * 16 + l15]
                        = __float2bfloat16(acc[mi][ni][r]);
                }
            }
        }
    }
}

// ====== shared down-GEMM with fused De reduce =================================
// out[t][c] = Hs[t]@Wsd[c] + sum_k De[starts[e_k]+inv_k][c]  (k=0..3 order)
__global__ __launch_bounds__(256) void downfuse(const bf16* __restrict__ Hs,
        const bf16* __restrict__ Wsd, const bf16* __restrict__ De,
        const int* __restrict__ tidx, const int* __restrict__ inv,
        const int* __restrict__ starts, float* __restrict__ out, int K) {
    __shared__ __align__(128) char Al[16384];
    __shared__ __align__(128) char Bl[16384];
    __shared__ int sst[8];
    const int tid = threadIdx.x, lane = tid & 63, wid = tid >> 6;
    if (tid < 8) sst[tid] = starts[tid];
    const long m0 = (long)blockIdx.y * 128;
    const long n0 = (long)blockIdx.x * 128;
    const int wm = (wid >> 1) * 64, wn = (wid & 1) * 64;
    const int l15 = lane & 15, lhi = lane >> 4;
    f32x4 acc[4][4] = {};
    for (int kt = 0; kt < K; kt += 64) {
        stage<128>(Hs + m0 * K + kt, (long)K, Al, tid);
        stage<128>(Wsd + n0 * K + kt, (long)K, Bl, tid);
        __syncthreads();
        #pragma unroll
        for (int ks = 0; ks < 2; ks++) {
            const int kb = ks * 64 + lhi * 16;
            i32x4 af[4], bfr[4];
            #pragma unroll
            for (int mi = 0; mi < 4; mi++) af[mi]  = ldsfrag(Al, wm + mi * 16 + l15, kb);
            #pragma unroll
            for (int ni = 0; ni < 4; ni++) bfr[ni] = ldsfrag(Bl, wn + ni * 16 + l15, kb);
            #pragma unroll
            for (int mi = 0; mi < 4; mi++) {
                #pragma unroll
                for (int ni = 0; ni < 4; ni++) mfma16(acc[mi][ni], af[mi], bfr[ni]);
            }
        }
        __syncthreads();
    }
    asm volatile("s_nop 7\n\ts_nop 7\n\ts_nop 7");
    #pragma unroll
    for (int mi = 0; mi < 4; mi++) {
        #pragma unroll
        for (int r = 0; r < 4; r++) {
            const long t = m0 + wm + mi * 16 + lhi * 4 + r;
            const int4 e4 = ((const int4*)tidx)[t];
            const int4 p4 = ((const int4*)inv)[t];
            long rr[4];
            rr[0] = (long)sst[e4.x] + p4.x; rr[1] = (long)sst[e4.y] + p4.y;
            rr[2] = (long)sst[e4.z] + p4.z; rr[3] = (long)sst[e4.w] + p4.w;
            #pragma unroll
            for (int ni = 0; ni < 4; ni++) {
                const long col = n0 + wn + ni * 16 + l15;
                float v = acc[mi][ni][r];
                #pragma unroll
                for (int k = 0; k < 4; k++)
                    v += __bfloat162float(De[rr[k] * 2048 + col]);
                out[t * 2048 + col] = v;
            }
        }
    }
}

// ====== standalone reduce (fallback path) ======
__global__ __launch_bounds__(256) void reduce4(const bf16* __restrict__ De,
        const int* __restrict__ tidx, const int* __restrict__ inv,
        const int* __restrict__ starts, float* __restrict__ out) {
    const long t = blockIdx.x;
    const int c = threadIdx.x * 8;
    const int4 e4 = ((const int4*)tidx)[t];
    const int4 p4 = ((const int4*)inv)[t];
    long r[4];
    r[0] = (long)starts[e4.x] + p4.x; r[1] = (long)starts[e4.y] + p4.y;
    r[2] = (long)starts[e4.z] + p4.z; r[3] = (long)starts[e4.w] + p4.w;
    float4* o = (float4*)(out + t * 2048 + c);
    float4 o0 = o[0], o1 = o[1];
    float acc[8] = { o0.x, o0.y, o0.z, o0.w, o1.x, o1.y, o1.z, o1.w };
    #pragma unroll
    for (int k = 0; k < 4; k++) {
        const uint4 v = *(const uint4*)(De + r[k] * 2048 + c);
        const unsigned w[4] = { v.x, v.y, v.z, v.w };
        #pragma unroll
        for (int j = 0; j < 4; j++) {
            union { unsigned u; float f; } lo, hi;
            lo.u = (w[j] & 0xffffu) << 16;
            hi.u = w[j] & 0xffff0000u;
            acc[j * 2]     += lo.f;
            acc[j * 2 + 1] += hi.f;
        }
    }
    o[0] = make_float4(acc[0], acc[1], acc[2], acc[3]);
    o[1] = make_float4(acc[4], acc[5], acc[6], acc[7]);
}

extern "C" void kernel_launch(void* const* d_in, const int* in_sizes, int n_in,
                              void* d_out, int out_size, void* d_ws, size_t ws_size,
                              hipStream_t stream) {
    const int N = 8192, Cdim = 2048, E = 8, I = 1408, SI = 5632;

    const float* x    = (const float*)d_in[0];
    const float* gw   = (const float*)d_in[1];
    const float* egw  = (const float*)d_in[2];
    const float* euw  = (const float*)d_in[3];
    const float* edw  = (const float*)d_in[4];
    const float* sgw  = (const float*)d_in[5];
    const float* suw  = (const float*)d_in[6];
    const float* sdw  = (const float*)d_in[7];
    const float* segw = (const float*)d_in[8];
    float* out = (float*)d_out;

    char* ws = (char*)d_ws;
    size_t off = 0;
    auto alloc = [&](size_t bytes) { char* p = ws + off; off += (bytes + 255) & ~(size_t)255; return p; };

    bf16*  xb     = (bf16*) alloc((size_t)N * Cdim * 2);   // dead after megadual
    int*   tidx   = (int*)  alloc((size_t)N * 4 * 4);
    float* tw     = (float*)alloc((size_t)N * 4 * 4);
    float* sg     = (float*)alloc((size_t)N * 4);
    int*   tok    = (int*)  alloc((size_t)E * N * 4);
    float* wl     = (float*)alloc((size_t)E * N * 4);
    int*   inv    = (int*)  alloc((size_t)N * 4 * 4);
    int*   cnt    = (int*)  alloc(256);
    int*   starts = (int*)  alloc(256);
    const size_t commonEnd = off;

    const size_t EWSLOT = (size_t)E * I * Cdim * 2;   // 46.1 MB
    const size_t SWSLOT = (size_t)SI * Cdim * 2;      // 23.1 MB
    const size_t HROWS  = (size_t)4 * N;
    const size_t mergedNeed = commonEnd + 2 * EWSLOT + 2 * SWSLOT
                            + (size_t)N * SI * 2 + HROWS * I * 2 + 4096;

    cvtrt<<<N / 4, 256, 0, stream>>>(x, gw, segw, xb, tidx, tw, sg);
    build_lists<<<E, 256, 0, stream>>>(tidx, tw, tok, wl, cnt, inv, N);
    scan8<<<1, 64, 0, stream>>>(cnt, starts);

    if (ws_size >= mergedNeed) {
        char* wreg = (char*)alloc(2 * EWSLOT + 2 * SWSLOT);  // 138.7 MB
        bf16* Wea = (bf16*)wreg;
        bf16* Web = (bf16*)(wreg + EWSLOT);
        bf16* Wsa = (bf16*)(wreg + 2 * EWSLOT);
        bf16* Wsb = (bf16*)(wreg + 2 * EWSLOT + SWSLOT);
        bf16* Hs  = (bf16*)alloc((size_t)N * SI * 2);        // 92.3 MB
        bf16* He  = (bf16*)alloc(HROWS * I * 2);             // 92.3 MB
        // Phase-2 overlays (all regions dead by then; peak == mergedNeed):
        bf16* De   = (bf16*)wreg;     // 134.4 <= 138.7 (weights dead)
        bf16* Wedh = xb;              // 4-expert half: 23.1 <= 33.6 (xb dead)
        bf16* Wsd  = He;              // 23.1 <= 92.3 (He dead after megadowns)

        convt_gu<<<dim3(22, 32, 24), 256, 0, stream>>>(
                egw, euw, sgw, suw, Wea, Web, Wsa, Wsb);
        megadual<<<dim3(N / 128, I / 64, E + 4), 256, 0, stream>>>(xb,
                tok, cnt, starts, E, 0, Wea, Web, (long)I * Cdim,
                Wsa, Wsb, He, Hs, wl, sg, Cdim);

        // expert downs in two 4-expert halves -> compact De
        convt_dne<<<dim3(32, 22, 4), 256, 0, stream>>>(edw, Wedh);
        megadown<<<dim3(Cdim / 128, N / 128, 4), 256, 0, stream>>>(
                He, Wedh, (long)Cdim * I, De, cnt, starts, I);
        convt_dne<<<dim3(32, 22, 4), 256, 0, stream>>>(
                edw + (long)4 * I * Cdim, Wedh);
        megadown<<<dim3(Cdim / 128, N / 128, 4), 256, 0, stream>>>(
                He, Wedh, (long)Cdim * I, De, cnt + 4, starts + 4, I);

        // shared down + fused De reduce -> out (single pass, bitwise == R11)
        convt_dns<<<dim3(32, 22, 4), 256, 0, stream>>>(sdw, Wsd);
        downfuse<<<dim3(Cdim / 128, N / 128), 256, 0, stream>>>(
                Hs, Wsd, De, tidx, inv, starts, out, SI);
        return;
    }

    // -------- deep fallback (ws < merged plan; sequential EB=4) --------
    bf16* Wa = (bf16*)alloc(SWSLOT);
    bf16* Wb = (bf16*)alloc(SWSLOT);
    bf16* Wc = (bf16*)alloc(SWSLOT);
    bf16* Hs = (bf16*)alloc((size_t)N * SI * 2);
    bf16* He = (bf16*)alloc(HROWS * I * 2);
    if (off > ws_size) return;

    tcvt<<<dim3(SI / 64, Cdim / 64, 2), 256, 0, stream>>>(
            sgw, Wa, suw, Wb, SI, (long)Cdim, 0, 0, 1);
    tcvt<<<dim3(Cdim / 64, SI / 64, 1), 256, 0, stream>>>(
            sdw, Wc, nullptr, nullptr, Cdim, (long)SI, 0, 0, 1);
    megadual<<<dim3(N / 128, I / 64, 4), 256, 0, stream>>>(xb,
            tok, cnt, starts, 0, 0, nullptr, nullptr, 0,
            Wa, Wb, nullptr, Hs, wl, sg, Cdim);
    gemm_down_t<0><<<dim3(Cdim / 128, N / 128), 256, 0, stream>>>(
            Hs, Wc, out, nullptr, nullptr, N, nullptr, 0, 0, SI, (long)Cdim, 0);

    for (int b = 0; b < 2; b++) {
        const int e0 = b * 4;
        tcvt<<<dim3(I / 64, Cdim / 64, 8), 256, 0, stream>>>(
                egw + (long)e0 * Cdim * I, Wa, euw + (long)e0 * Cdim * I, Wb,
                I, (long)Cdim, (long)Cdim * I, (long)I * Cdim, 4);
        megadual<<<dim3(N / 128, I / 64, 4), 256, 0, stream>>>(xb,
                tok, cnt, starts, 4, e0, Wa, Wb, (long)I * Cdim,
                nullptr, nullptr, He, nullptr, wl, sg, Cdim);
        tcvt<<<dim3(Cdim / 64, I / 64, 4), 256, 0, stream>>>(
                edw + (long)e0 * I * Cdim, Wc, nullptr, nullptr,
                Cdim, (long)I, (long)I * Cdim, (long)Cdim * I, 4);
        for (int z = 0; z < 4; z++) {
            gemm_down_t<1><<<dim3(Cdim / 128, N / 128), 256, 0, stream>>>(
                    He, Wc + (long)z * Cdim * I, out,
                    tok + (long)(e0 + z) * N, cnt + e0 + z, 0,
                    starts, e0 + z, e0, I, (long)Cdim, 1);
        }
    }
}

// Round 15
// 1377.442 us; speedup vs baseline: 1.0389x; 1.0389x over previous
//
#include <hip/hip_runtime.h>
#include <hip/hip_bf16.h>
#include <stdint.h>

// R15: revert to exact R10 (best measured: 1386.7us). R11-R14 variations were
// neutral-to-negative (vectorized converts neutral; fused reduce negative due
// to half-batch co-fill loss; pipelined down8 neutral). Final configuration:
// cvtrt+build_lists+scan8 -> tcvt converts -> megadual (E+4 co-fill) ->
// shared gemm_down (beta=0) -> z=8 megadown -> reduce4.

typedef float f32x4 __attribute__((ext_vector_type(4)));
typedef int   i32x4 __attribute__((ext_vector_type(4)));
typedef __hip_bfloat16 bf16;

#define DEV __device__ __forceinline__

DEV void mfma16(f32x4& c, const i32x4& a, const i32x4& b) {
    asm("v_mfma_f32_16x16x32_bf16 %0, %1, %2, %0" : "+v"(c) : "v"(a), "v"(b));
}

// Direct stage: [ROWS][64] bf16 tile (row stride ldK elems) -> LDS linear,
// T2 XOR swizzle applied on the global source (rule #21).
template<int ROWS>
DEV void stage(const bf16* gtile, long ldK, char* lds, int tid) {
    const int wid = tid >> 6, lane = tid & 63;
    const int swz = ((lane & 7) ^ (lane >> 3)) << 4;
    constexpr int NISS = (ROWS * 128) / 4096;
    #pragma unroll
    for (int i = 0; i < NISS; i++) {
        const int o = i * 4096 + wid * 1024;
        const int row = (o >> 7) + (lane >> 3);
        const char* ga = (const char*)gtile + (long)row * (ldK * 2) + swz;
        __builtin_amdgcn_global_load_lds(
            (const __attribute__((address_space(1))) void*)ga,
            (__attribute__((address_space(3))) void*)(lds + o), 16, 0, 0);
    }
}

// Indirect stage: per-lane row byte-offsets precomputed (gathered rows).
template<int ROWS>
DEV void stage_idx(const char* base, const long* roff, int ktb, char* lds,
                   int tid, int swz) {
    const int wid = tid >> 6;
    constexpr int NISS = (ROWS * 128) / 4096;
    #pragma unroll
    for (int i = 0; i < NISS; i++) {
        const int o = i * 4096 + wid * 1024;
        const char* ga = base + roff[i] + ktb + swz;
        __builtin_amdgcn_global_load_lds(
            (const __attribute__((address_space(1))) void*)ga,
            (__attribute__((address_space(3))) void*)(lds + o), 16, 0, 0);
    }
}

DEV i32x4 ldsfrag(const char* lds, int row, int kbyte) {
    const int off = (row << 7) + (kbyte ^ ((row & 7) << 4));
    return *(const i32x4*)(lds + off);
}

// ---------------- transpose + fp32->bf16 convert (z-batched, dual-src) ------
__global__ __launch_bounds__(256) void tcvt(const float* __restrict__ srcA,
        bf16* __restrict__ dstA, const float* __restrict__ srcB,
        bf16* __restrict__ dstB, int Cd, long dld, long sz, long dz,
        int zsplit) {
    __shared__ float t[64][65];
    long z = blockIdx.z;
    const float* src; bf16* dst;
    if ((int)z < zsplit) { src = srcA; dst = dstA; }
    else { src = srcB; dst = dstB; z -= zsplit; }
    src += z * sz; dst += z * dz;
    const int cb = blockIdx.x * 64, rb = blockIdx.y * 64;
    const int tx = threadIdx.x & 63, ty = threadIdx.x >> 6;
    #pragma unroll
    for (int i = 0; i < 16; i++) {
        const int r = ty + i * 4;
        t[r][tx] = src[(long)(rb + r) * Cd + cb + tx];
    }
    __syncthreads();
    #pragma unroll
    for (int i = 0; i < 16; i++) {
        const int c = ty + i * 4;
        dst[(long)(cb + c) * dld + rb + tx] = __float2bfloat16(t[tx][c]);
    }
}

// ------- fused x convert + router (fp32 logits, softmax, top-4, renorm) -----
__global__ __launch_bounds__(256) void cvtrt(const float* __restrict__ x,
        const float* __restrict__ gw, const float* __restrict__ segw,
        bf16* __restrict__ xb, int* __restrict__ tidx, float* __restrict__ tw,
        float* __restrict__ sg) {
    const int lane = threadIdx.x & 63;
    const long t = (long)blockIdx.x * 4 + (threadIdx.x >> 6);
    const float4* xr = (const float4*)(x + t * 2048);
    ushort4* xo = (ushort4*)(xb + t * 2048);
    float a[9];
    #pragma unroll
    for (int e = 0; e < 9; e++) a[e] = 0.f;
    #pragma unroll
    for (int i = 0; i < 8; i++) {
        const int c4 = i * 64 + lane;
        const float4 v = xr[c4];
        union { bf16 h[4]; ushort4 u; } cu;
        cu.h[0] = __float2bfloat16(v.x); cu.h[1] = __float2bfloat16(v.y);
        cu.h[2] = __float2bfloat16(v.z); cu.h[3] = __float2bfloat16(v.w);
        xo[c4] = cu.u;
        const int c = c4 * 4;
        const float xv[4] = { v.x, v.y, v.z, v.w };
        #pragma unroll
        for (int j = 0; j < 4; j++) {
            const float4* g4 = (const float4*)(gw + (long)(c + j) * 8);
            const float4 g0 = g4[0], g1 = g4[1];
            a[0] += xv[j] * g0.x; a[1] += xv[j] * g0.y;
            a[2] += xv[j] * g0.z; a[3] += xv[j] * g0.w;
            a[4] += xv[j] * g1.x; a[5] += xv[j] * g1.y;
            a[6] += xv[j] * g1.z; a[7] += xv[j] * g1.w;
            a[8] += xv[j] * segw[c + j];
        }
    }
    #pragma unroll
    for (int e = 0; e < 9; e++) {
        #pragma unroll
        for (int o = 32; o; o >>= 1) a[e] += __shfl_xor(a[e], o, 64);
    }
    if (lane == 0) {
        float m = a[0];
        #pragma unroll
        for (int e = 1; e < 8; e++) m = fmaxf(m, a[e]);
        float p[8]; float s = 0.f;
        #pragma unroll
        for (int e = 0; e < 8; e++) { p[e] = expf(a[e] - m); s += p[e]; }
        #pragma unroll
        for (int e = 0; e < 8; e++) p[e] /= s;
        bool used[8] = {false,false,false,false,false,false,false,false};
        float wsum = 0.f; int idx[4]; float wv[4];
        for (int k = 0; k < 4; k++) {       // strict > : lowest index on ties
            float best = -1.f; int bi = 0;
            for (int e = 0; e < 8; e++)
                if (!used[e] && p[e] > best) { best = p[e]; bi = e; }
            used[bi] = true; idx[k] = bi; wv[k] = best; wsum += best;
        }
        int4 iv; float4 wv4;
        iv.x = idx[0]; iv.y = idx[1]; iv.z = idx[2]; iv.w = idx[3];
        wv4.x = wv[0] / wsum; wv4.y = wv[1] / wsum;
        wv4.z = wv[2] / wsum; wv4.w = wv[3] / wsum;
        ((int4*)tidx)[t] = iv;
        ((float4*)tw)[t] = wv4;
        sg[t] = 1.f / (1.f + expf(-a[8]));
    }
}

// ------ per-expert ordered token lists + inverse slot map (deterministic) ---
__global__ __launch_bounds__(256) void build_lists(const int* __restrict__ tidx,
        const float* __restrict__ tw, int* __restrict__ tok,
        float* __restrict__ wl, int* __restrict__ cnt, int* __restrict__ inv,
        int N) {
    const int e = blockIdx.x;
    const int tid = threadIdx.x;
    const int per = N / 256;
    __shared__ int csum[256];
    int c = 0;
    for (int i = 0; i < per; i++) {
        const int4 id4 = ((const int4*)tidx)[tid * per + i];
        if (id4.x == e || id4.y == e || id4.z == e || id4.w == e) c++;
    }
    csum[tid] = c;
    __syncthreads();
    for (int o = 1; o < 256; o <<= 1) {
        const int v = (tid >= o) ? csum[tid - o] : 0;
        __syncthreads();
        csum[tid] += v;
        __syncthreads();
    }
    int pos = csum[tid] - c;
    if (tid == 255) cnt[e] = csum[255];
    for (int i = 0; i < per; i++) {
        const int t = tid * per + i;
        const int4   id4 = ((const int4*)tidx)[t];
        const float4 w4  = ((const float4*)tw)[t];
        float w = 0.f; int hit = 0; int k = 0;
        if      (id4.x == e) { w = w4.x; hit = 1; k = 0; }
        else if (id4.y == e) { w = w4.y; hit = 1; k = 1; }
        else if (id4.z == e) { w = w4.z; hit = 1; k = 2; }
        else if (id4.w == e) { w = w4.w; hit = 1; k = 3; }
        if (hit) {
            tok[(long)e * N + pos] = t;
            wl[(long)e * N + pos] = w;
            inv[t * 4 + k] = pos;
            pos++;
        }
    }
}

// ---------------- starts = exclusive prefix of cnt --------------------------
__global__ void scan8(const int* __restrict__ cnt, int* __restrict__ starts) {
    if (threadIdx.x == 0) {
        int s = 0;
        for (int e = 0; e < 8; e++) { starts[e] = s; s += cnt[e]; }
        starts[8] = s;
    }
}

// ======== mega dual gate/up GEMM: z<nExpZ experts, z>=nExpZ shared ==========
__global__ __launch_bounds__(256) void megadual(const bf16* __restrict__ A0,
        const int* __restrict__ tok, const int* __restrict__ cnt,
        const int* __restrict__ starts, int nExpZ, int e0,
        const bf16* __restrict__ Wea, const bf16* __restrict__ Web, long ebz,
        const bf16* __restrict__ Wsa, const bf16* __restrict__ Wsb,
        bf16* __restrict__ He, bf16* __restrict__ Hs,
        const float* __restrict__ wl, const float* __restrict__ sg, int K) {
    __shared__ __align__(128) char Al[16384];
    __shared__ __align__(128) char Gl[8192];
    __shared__ __align__(128) char Ul[8192];
    const int z = blockIdx.z;
    const bf16 *BG, *BU; bf16* H; long hld, n0; const float* sc;
    const int* ridx; int Me;
    if (z < nExpZ) {
        const int e = e0 + z;
        Me = cnt[e];
        ridx = tok + (long)e * 8192;
        BG = Wea + (long)z * ebz; BU = Web + (long)z * ebz;
        H = He + ((long)starts[e] - starts[e0]) * 1408;
        hld = 1408; sc = wl + (long)e * 8192;
        n0 = (long)blockIdx.y * 64;
    } else {
        Me = 8192; ridx = nullptr;
        BG = Wsa; BU = Wsb; H = Hs; hld = 5632; sc = sg;
        n0 = (long)((z - nExpZ) * gridDim.y + blockIdx.y) * 64;
    }
    const long m0 = (long)blockIdx.x * 128;
    if (m0 >= Me) return;
    const int tid = threadIdx.x, lane = tid & 63, wid = tid >> 6;
    const int wm = (wid >> 1) * 64, wn = (wid & 1) * 32;
    const int l15 = lane & 15, lhi = lane >> 4;
    const int swz = ((lane & 7) ^ (lane >> 3)) << 4;
    long roffA[4];
    #pragma unroll
    for (int i = 0; i < 4; i++) {
        const int rit = ((i * 4096 + wid * 1024) >> 7) + (lane >> 3);
        int g = (int)m0 + rit;
        if (ridx) g = ridx[g < Me ? g : Me - 1];
        roffA[i] = (long)g * (K * 2);
    }
    f32x4 ag[4][2] = {}; f32x4 au[4][2] = {};
    for (int kt = 0; kt < K; kt += 64) {
        stage_idx<128>((const char*)A0, roffA, kt * 2, Al, tid, swz);
        stage<64>(BG + n0 * K + kt, (long)K, Gl, tid);
        stage<64>(BU + n0 * K + kt, (long)K, Ul, tid);
        __syncthreads();
        #pragma unroll
        for (int ks = 0; ks < 2; ks++) {
            const int kb = ks * 64 + lhi * 16;
            i32x4 af[4], bg[2], bu[2];
            #pragma unroll
            for (int mi = 0; mi < 4; mi++) af[mi] = ldsfrag(Al, wm + mi * 16 + l15, kb);
            #pragma unroll
            for (int ni = 0; ni < 2; ni++) {
                bg[ni] = ldsfrag(Gl, wn + ni * 16 + l15, kb);
                bu[ni] = ldsfrag(Ul, wn + ni * 16 + l15, kb);
            }
            #pragma unroll
            for (int mi = 0; mi < 4; mi++) {
                #pragma unroll
                for (int ni = 0; ni < 2; ni++) {
                    mfma16(ag[mi][ni], af[mi], bg[ni]);
                    mfma16(au[mi][ni], af[mi], bu[ni]);
                }
            }
        }
        __syncthreads();
    }
    asm volatile("s_nop 7\n\ts_nop 7\n\ts_nop 7");
    #pragma unroll
    for (int mi = 0; mi < 4; mi++) {
        #pragma unroll
        for (int r = 0; r < 4; r++) {
            const int pos = (int)m0 + wm + mi * 16 + lhi * 4 + r;
            if (pos < Me) {
                const float s = sc[pos];
                #pragma unroll
                for (int ni = 0; ni < 2; ni++) {
                    const float gv = ag[mi][ni][r], uv = au[mi][ni][r];
                    const float h = (gv / (1.f + expf(-gv))) * uv * s;
                    H[(long)pos * hld + n0 + wn + ni * 16 + l15] = __float2bfloat16(h);
                }
            }
        }
    }
}

// ------ down GEMM: C[row(pos)] (+)= A[pos,:K] * BT^T, scatter rows ----------
template<int TAG>
__global__ __launch_bounds__(256) void gemm_down_t(const bf16* __restrict__ A,
        const bf16* __restrict__ BT, float* __restrict__ C,
        const int* __restrict__ ridx, const int* __restrict__ cntp, int Mfix,
        const int* __restrict__ starts, int ia, int ib,
        int K, long ldc, int beta) {
    __shared__ __align__(128) char Al[16384];
    __shared__ __align__(128) char Bl[16384];
    const int Me = cntp ? *cntp : Mfix;
    const long m0 = (long)blockIdx.y * 128;
    if (m0 >= Me) return;
    if (starts) A += ((long)starts[ia] - starts[ib]) * K;
    const int tid = threadIdx.x, lane = tid & 63, wid = tid >> 6;
    const long n0 = (long)blockIdx.x * 128;
    const int wm = (wid >> 1) * 64, wn = (wid & 1) * 64;
    const int l15 = lane & 15, lhi = lane >> 4;
    f32x4 acc[4][4] = {};
    for (int kt = 0; kt < K; kt += 64) {
        stage<128>(A  + m0 * K + kt, (long)K, Al, tid);
        stage<128>(BT + n0 * K + kt, (long)K, Bl, tid);
        __syncthreads();
        #pragma unroll
        for (int ks = 0; ks < 2; ks++) {
            const int kb = ks * 64 + lhi * 16;
            i32x4 af[4], bfr[4];
            #pragma unroll
            for (int mi = 0; mi < 4; mi++) af[mi]  = ldsfrag(Al, wm + mi * 16 + l15, kb);
            #pragma unroll
            for (int ni = 0; ni < 4; ni++) bfr[ni] = ldsfrag(Bl, wn + ni * 16 + l15, kb);
            #pragma unroll
            for (int mi = 0; mi < 4; mi++) {
                #pragma unroll
                for (int ni = 0; ni < 4; ni++) mfma16(acc[mi][ni], af[mi], bfr[ni]);
            }
        }
        __syncthreads();
    }
    asm volatile("s_nop 7\n\ts_nop 7\n\ts_nop 7");
    #pragma unroll
    for (int mi = 0; mi < 4; mi++) {
        #pragma unroll
        for (int r = 0; r < 4; r++) {
            const int pos = (int)m0 + wm + mi * 16 + lhi * 4 + r;
            if (pos < Me) {
                const long orow = ridx ? (long)ridx[pos] : (long)pos;
                #pragma unroll
                for (int ni = 0; ni < 4; ni++) {
                    const long ci = orow * ldc + n0 + wn + ni * 16 + l15;
                    float v = acc[mi][ni][r];
                    if (beta) v += C[ci];
                    C[ci] = v;
                }
            }
        }
    }
}

// ====== expert mega-down: De[starts[z]+pos] = He[starts[z]+pos] @ Wd_z^T ====
__global__ __launch_bounds__(256) void megadown(const bf16* __restrict__ He,
        const bf16* __restrict__ Wd0, long wz, bf16* __restrict__ De,
        const int* __restrict__ cnt, const int* __restrict__ starts, int K) {
    __shared__ __align__(128) char Al[16384];
    __shared__ __align__(128) char Bl[16384];
    const int z = blockIdx.z;
    const int Me = cnt[z];
    const long m0 = (long)blockIdx.y * 128;
    if (m0 >= Me) return;
    const bf16* A  = He + (long)starts[z] * K;
    const bf16* BT = Wd0 + (long)z * wz;
    const int tid = threadIdx.x, lane = tid & 63, wid = tid >> 6;
    const long n0 = (long)blockIdx.x * 128;
    const int wm = (wid >> 1) * 64, wn = (wid & 1) * 64;
    const int l15 = lane & 15, lhi = lane >> 4;
    f32x4 acc[4][4] = {};
    for (int kt = 0; kt < K; kt += 64) {
        stage<128>(A  + m0 * K + kt, (long)K, Al, tid);
        stage<128>(BT + n0 * K + kt, (long)K, Bl, tid);
        __syncthreads();
        #pragma unroll
        for (int ks = 0; ks < 2; ks++) {
            const int kb = ks * 64 + lhi * 16;
            i32x4 af[4], bfr[4];
            #pragma unroll
            for (int mi = 0; mi < 4; mi++) af[mi]  = ldsfrag(Al, wm + mi * 16 + l15, kb);
            #pragma unroll
            for (int ni = 0; ni < 4; ni++) bfr[ni] = ldsfrag(Bl, wn + ni * 16 + l15, kb);
            #pragma unroll
            for (int mi = 0; mi < 4; mi++) {
                #pragma unroll
                for (int ni = 0; ni < 4; ni++) mfma16(acc[mi][ni], af[mi], bfr[ni]);
            }
        }
        __syncthreads();
    }
    asm volatile("s_nop 7\n\ts_nop 7\n\ts_nop 7");
    #pragma unroll
    for (int mi = 0; mi < 4; mi++) {
        #pragma unroll
        for (int r = 0; r < 4; r++) {
            const int pos = (int)m0 + wm + mi * 16 + lhi * 4 + r;
            if (pos < Me) {
                const long orow = (long)starts[z] + pos;
                #pragma unroll
                for (int ni = 0; ni < 4; ni++) {
                    De[orow * 2048 + n0 + wn + ni * 16 + l15]
                        = __float2bfloat16(acc[mi][ni][r]);
                }
            }
        }
    }
}

// ====== reduce: out[t] += sum_k De[starts[e_k]+inv_k]  (fixed slot order) ===
__global__ __launch_bounds__(256) void reduce4(const bf16* __restrict__ De,
        const int* __restrict__ tidx, const int* __restrict__ inv,
        const int* __restrict__ starts, float* __restrict__ out) {
    const long t = blockIdx.x;
    const int c = threadIdx.x * 8;
    const int4 e4 = ((const int4*)tidx)[t];
    const int4 p4 = ((const int4*)inv)[t];
    long r[4];
    r[0] = (long)starts[e4.x] + p4.x; r[1] = (long)starts[e4.y] + p4.y;
    r[2] = (long)starts[e4.z] + p4.z; r[3] = (long)starts[e4.w] + p4.w;
    float4* o = (float4*)(out + t * 2048 + c);
    float4 o0 = o[0], o1 = o[1];
    float acc[8] = { o0.x, o0.y, o0.z, o0.w, o1.x, o1.y, o1.z, o1.w };
    #pragma unroll
    for (int k = 0; k < 4; k++) {
        const uint4 v = *(const uint4*)(De + r[k] * 2048 + c);
        const unsigned w[4] = { v.x, v.y, v.z, v.w };
        #pragma unroll
        for (int j = 0; j < 4; j++) {
            union { unsigned u; float f; } lo, hi;
            lo.u = (w[j] & 0xffffu) << 16;
            hi.u = w[j] & 0xffff0000u;
            acc[j * 2]     += lo.f;
            acc[j * 2 + 1] += hi.f;
        }
    }
    o[0] = make_float4(acc[0], acc[1], acc[2], acc[3]);
    o[1] = make_float4(acc[4], acc[5], acc[6], acc[7]);
}

extern "C" void kernel_launch(void* const* d_in, const int* in_sizes, int n_in,
                              void* d_out, int out_size, void* d_ws, size_t ws_size,
                              hipStream_t stream) {
    const int N = 8192, Cdim = 2048, E = 8, I = 1408, SI = 5632;

    const float* x    = (const float*)d_in[0];
    const float* gw   = (const float*)d_in[1];
    const float* egw  = (const float*)d_in[2];
    const float* euw  = (const float*)d_in[3];
    const float* edw  = (const float*)d_in[4];
    const float* sgw  = (const float*)d_in[5];
    const float* suw  = (const float*)d_in[6];
    const float* sdw  = (const float*)d_in[7];
    const float* segw = (const float*)d_in[8];
    float* out = (float*)d_out;

    char* ws = (char*)d_ws;
    size_t off = 0;
    auto alloc = [&](size_t bytes) { char* p = ws + off; off += (bytes + 255) & ~(size_t)255; return p; };

    bf16*  xb     = (bf16*) alloc((size_t)N * Cdim * 2);   // dead after megadual
    int*   tidx   = (int*)  alloc((size_t)N * 4 * 4);
    float* tw     = (float*)alloc((size_t)N * 4 * 4);
    float* sg     = (float*)alloc((size_t)N * 4);
    int*   tok    = (int*)  alloc((size_t)E * N * 4);
    float* wl     = (float*)alloc((size_t)E * N * 4);
    int*   inv    = (int*)  alloc((size_t)N * 4 * 4);
    int*   cnt    = (int*)  alloc(256);
    int*   starts = (int*)  alloc(256);
    const size_t commonEnd = off;

    const size_t EWSLOT = (size_t)E * I * Cdim * 2;   // 46.24 MB
    const size_t SWSLOT = (size_t)SI * Cdim * 2;      // 23.12 MB
    const size_t HROWS  = (size_t)4 * N;              // sum cnt == 4N exactly
    const size_t mergedNeed = commonEnd + 2 * EWSLOT + 2 * SWSLOT
                            + (size_t)N * SI * 2 + HROWS * I * 2 + 4096;

    cvtrt<<<N / 4, 256, 0, stream>>>(x, gw, segw, xb, tidx, tw, sg);
    build_lists<<<E, 256, 0, stream>>>(tidx, tw, tok, wl, cnt, inv, N);
    scan8<<<1, 64, 0, stream>>>(cnt, starts);

    if (ws_size >= mergedNeed) {
        char* wreg = (char*)alloc(2 * EWSLOT + 2 * SWSLOT);  // gate/up weights / De
        bf16* Wea = (bf16*)wreg;
        bf16* Web = (bf16*)(wreg + EWSLOT);
        bf16* Wsa = (bf16*)(wreg + 2 * EWSLOT);
        bf16* Wsb = (bf16*)(wreg + 2 * EWSLOT + SWSLOT);
        bf16* Hs  = (bf16*)alloc((size_t)N * SI * 2);        // 92.3 MB
        bf16* He  = (bf16*)alloc(HROWS * I * 2);             // 92.3 MB
        // Phase-2 overlays (regions dead by then):
        bf16* Wsd = xb;               // shared down W: 23.1 <= 33.6 (xb dead)
        bf16* Wed = Hs;               // expert down W: 46.2 <= 92.3 (Hs dead)
        bf16* De  = (bf16*)wreg;      // 134.4 <= 138.7 (gate/up weights dead)

        tcvt<<<dim3(SI / 64, Cdim / 64, 2), 256, 0, stream>>>(
                sgw, Wsa, suw, Wsb, SI, (long)Cdim, 0, 0, 1);
        tcvt<<<dim3(I / 64, Cdim / 64, 2 * E), 256, 0, stream>>>(
                egw, Wea, euw, Web, I, (long)Cdim,
                (long)Cdim * I, (long)I * Cdim, E);

        megadual<<<dim3(N / 128, I / 64, E + 4), 256, 0, stream>>>(xb,
                tok, cnt, starts, E, 0, Wea, Web, (long)I * Cdim,
                Wsa, Wsb, He, Hs, wl, sg, Cdim);

        // shared down: Hs @ Wsd -> d_out (beta=0 covers all rows/cols)
        tcvt<<<dim3(Cdim / 64, SI / 64, 1), 256, 0, stream>>>(
                sdw, Wsd, nullptr, nullptr, Cdim, (long)SI, 0, 0, 1);
        gemm_down_t<0><<<dim3(Cdim / 128, N / 128), 256, 0, stream>>>(
                Hs, Wsd, out, nullptr, nullptr, N, nullptr, 0, 0,
                SI, (long)Cdim, 0);

        // expert mega-down: conflict-free compact De, then ordered reduce
        tcvt<<<dim3(Cdim / 64, I / 64, E), 256, 0, stream>>>(
                edw, Wed, nullptr, nullptr, Cdim, (long)I,
                (long)I * Cdim, (long)Cdim * I, E);
        megadown<<<dim3(Cdim / 128, N / 128, E), 256, 0, stream>>>(
                He, Wed, (long)Cdim * I, De, cnt, starts, I);
        reduce4<<<N, 256, 0, stream>>>(De, tidx, inv, starts, out);
        return;
    }

    // -------- fallback (ws < merged plan; sequential, EB=4) --------
    bf16* Wa = (bf16*)alloc(SWSLOT);
    bf16* Wb = (bf16*)alloc(SWSLOT);
    bf16* Wc = (bf16*)alloc(SWSLOT);
    bf16* Hs = (bf16*)alloc((size_t)N * SI * 2);
    bf16* He = (bf16*)alloc(HROWS * I * 2);
    if (off > ws_size) return;

    tcvt<<<dim3(SI / 64, Cdim / 64, 2), 256, 0, stream>>>(
            sgw, Wa, suw, Wb, SI, (long)Cdim, 0, 0, 1);
    tcvt<<<dim3(Cdim / 64, SI / 64, 1), 256, 0, stream>>>(
            sdw, Wc, nullptr, nullptr, Cdim, (long)SI, 0, 0, 1);
    megadual<<<dim3(N / 128, I / 64, 4), 256, 0, stream>>>(xb,
            tok, cnt, starts, 0, 0, nullptr, nullptr, 0,
            Wa, Wb, nullptr, Hs, wl, sg, Cdim);
    gemm_down_t<0><<<dim3(Cdim / 128, N / 128), 256, 0, stream>>>(
            Hs, Wc, out, nullptr, nullptr, N, nullptr, 0, 0, SI, (long)Cdim, 0);

    for (int b = 0; b < 2; b++) {
        const int e0 = b * 4;
        tcvt<<<dim3(I / 64, Cdim / 64, 8), 256, 0, stream>>>(
                egw + (long)e0 * Cdim * I, Wa, euw + (long)e0 * Cdim * I, Wb,
                I, (long)Cdim, (long)Cdim * I, (long)I * Cdim, 4);
        megadual<<<dim3(N / 128, I / 64, 4), 256, 0, stream>>>(xb,
                tok, cnt, starts, 4, e0, Wa, Wb, (long)I * Cdim,
                nullptr, nullptr, He, nullptr, wl, sg, Cdim);
        tcvt<<<dim3(Cdim / 64, I / 64, 4), 256, 0, stream>>>(
                edw + (long)e0 * I * Cdim, Wc, nullptr, nullptr,
                Cdim, (long)I, (long)I * Cdim, (long)Cdim * I, 4);
        for (int z = 0; z < 4; z++) {
            gemm_down_t<1><<<dim3(Cdim / 128, N / 128), 256, 0, stream>>>(
                    He, Wc + (long)z * Cdim * I, out,
                    tok + (long)(e0 + z) * N, cnt + e0 + z, 0,
                    starts, e0 + z, e0, I, (long)Cdim, 1);
        }
    }
}